// Round 7
// baseline (106.928 us; speedup 1.0000x reference)
//
#include <hip/hip_runtime.h>
#include <hip/hip_fp16.h>

#define N_AG 512
#define TRAJ 16
#define TAU_ 2048
#define MSG_ 32768
#define HID_ 512
#define DV_ 64
#define SPLITQ 32
#define LDS_K 40            // 32 k-halves + 8 pad (proven layout)

typedef _Float16 f16x8 __attribute__((ext_vector_type(8)));
typedef _Float16 f16x4 __attribute__((ext_vector_type(4)));
typedef _Float16 f16x2 __attribute__((ext_vector_type(2)));
typedef float f32x4 __attribute__((ext_vector_type(4)));

// ---------------- prep: Wvt[c'][c] = (f16) Wv[c][c'] -----------------------
__global__ __launch_bounds__(256) void prep(const float* __restrict__ Wv,
                                            _Float16* __restrict__ Wvt)
{
    __shared__ float td[64][65];
    const int k0 = blockIdx.x * 64;
    for (int e = threadIdx.x; e < 4096; e += 256) {
        const int ki = e >> 6, ni = e & 63;
        td[ki][ni] = Wv[(size_t)(k0 + ki) * DV_ + ni];
    }
    __syncthreads();
    for (int e = threadIdx.x; e < 4096; e += 256) {
        const int ni = e >> 6, ki = e & 63;
        Wvt[(size_t)ni * TAU_ + k0 + ki] = (_Float16)td[ki][ni];
    }
}

// ---------------- generic tile: 128 x NB, BK=32, 4 waves (2x2) -------------
// A [128 x K] f32 row-major, B [K x NB] f32 row-major, C f16.
// fp32->fp16 fused into LDS staging; depth-2 reg prefetch + __syncthreads.
template<int NB>
__device__ __forceinline__ void gemm_tile(
    _Float16* __restrict__ As, _Float16* __restrict__ Bs,
    const float* __restrict__ Ag, int lda,
    const float* __restrict__ Bg, int ldb,
    _Float16* __restrict__ Cg, int ldc, int K)
{
    constexpr int NF = NB / 32;          // B-frags per wave (2 for NB=64)
    constexpr int BUFA = 128 * LDS_K;
    constexpr int BUFB = NB * LDS_K;
    const int tid = threadIdx.x;
    const int lane = tid & 63;
    const int wid = tid >> 6;
    const int wr = wid >> 1;
    const int wc = wid & 1;
    const int am = tid >> 1;
    const int ak = (tid & 1) << 4;

    int btn, btk;
    bool bact;
    if (NB == 128) { btn = tid & 31; btk = tid >> 5; bact = true; }
    else           { btn = tid & 15; btk = (tid >> 4) & 7; bact = (tid < 128); }

    const int arow = wr * 64 + (lane & 15);
    const int brow = wc * (NF * 16) + (lane & 15);
    const int kblk = (lane >> 4) << 3;

    f32x4 acc[4][NF];
#pragma unroll
    for (int mi = 0; mi < 4; ++mi)
#pragma unroll
        for (int ni = 0; ni < NF; ++ni)
            acc[mi][ni] = (f32x4){0.f, 0.f, 0.f, 0.f};

    float4 rA[8], rB[8];
    const int nt = K >> 5;

    auto load_stage = [&](float4 (&r)[8], int ks) {
        const float* ap = Ag + (size_t)am * lda + ks + ak;
#pragma unroll
        for (int i = 0; i < 4; ++i) r[i] = *(const float4*)(ap + 4 * i);
        if (bact) {
            const float* bp = Bg + (size_t)(ks + btk * 4) * ldb + btn * 4;
#pragma unroll
            for (int i = 0; i < 4; ++i) r[4 + i] = *(const float4*)(bp + (size_t)i * ldb);
        }
    };
    auto write_stage = [&](float4 (&r)[8], int buf) {
        _Float16* abase = As + buf * BUFA + am * LDS_K + ak;
        const float* fa = (const float*)&r[0];
        f16x8 h0, h1;
#pragma unroll
        for (int i = 0; i < 8; ++i) { h0[i] = (_Float16)fa[i]; h1[i] = (_Float16)fa[8 + i]; }
        *(f16x8*)abase = h0;
        *(f16x8*)(abase + 8) = h1;
        if (bact) {
            const float* fb = (const float*)&r[4];
#pragma unroll
            for (int j = 0; j < 4; ++j) {
                f16x4 wv;
#pragma unroll
                for (int i = 0; i < 4; ++i) wv[i] = (_Float16)fb[i * 4 + j];
                *(f16x4*)(Bs + buf * BUFB + (btn * 4 + j) * LDS_K + btk * 4) = wv;
            }
        }
    };
    auto compute = [&](int buf) {
        const _Float16* ab = As + buf * BUFA;
        const _Float16* bbp = Bs + buf * BUFB;
        f16x8 af[4], bf[NF];
#pragma unroll
        for (int mi = 0; mi < 4; ++mi)
            af[mi] = *(const f16x8*)(ab + (arow + mi * 16) * LDS_K + kblk);
#pragma unroll
        for (int ni = 0; ni < NF; ++ni)
            bf[ni] = *(const f16x8*)(bbp + (brow + ni * 16) * LDS_K + kblk);
#pragma unroll
        for (int mi = 0; mi < 4; ++mi)
#pragma unroll
            for (int ni = 0; ni < NF; ++ni)
                acc[mi][ni] = __builtin_amdgcn_mfma_f32_16x16x32_f16(
                    af[mi], bf[ni], acc[mi][ni], 0, 0, 0);
    };

    load_stage(rA, 0);
    load_stage(rB, 32);
    write_stage(rA, 0);
    __syncthreads();
    for (int t = 0; t < nt; t += 2) {
        if (t + 2 < nt) load_stage(rA, (t + 2) << 5);
        compute(0);
        if (t + 1 < nt) write_stage(rB, 1);
        __syncthreads();
        if (t + 3 < nt) load_stage(rB, (t + 3) << 5);
        compute(1);
        if (t + 2 < nt) write_stage(rA, 0);
        __syncthreads();
    }
    // C/D layout (HW-verified): col = lane&15, row = (lane>>4)*4 + reg
#pragma unroll
    for (int mi = 0; mi < 4; ++mi)
#pragma unroll
        for (int ni = 0; ni < NF; ++ni) {
            const int row = wr * 64 + mi * 16 + ((lane >> 4) << 2);
            const int col = wc * (NF * 16) + ni * 16 + (lane & 15);
#pragma unroll
            for (int r = 0; r < 4; ++r)
                Cg[(size_t)(row + r) * ldc + col] = (_Float16)acc[mi][ni][r];
        }
}

// qgemm: q partials, split-K=32, tiles 128x64 -> grid 1024 (4 blocks/CU).
__global__ __launch_bounds__(256, 4) void qgemm(const float* __restrict__ X,
                                                const float* __restrict__ Wq,
                                                _Float16* __restrict__ qpart)
{
    __shared__ __align__(16) _Float16 smem[2 * 128 * LDS_K + 2 * 64 * LDS_K];
    const int b = blockIdx.x;
    const int w = (b & 7) * 128 + (b >> 3);   // 1024 = 8 XCD chunks of 128
    const int s = w >> 5;                     // K-slice 0..31
    const int bm = (w >> 3) & 3;
    const int bn = w & 7;
    const int KS = MSG_ / SPLITQ;             // 1024
    gemm_tile<64>(smem, smem + 2 * 128 * LDS_K,
                  X + (size_t)bm * 128 * MSG_ + s * KS, MSG_,
                  Wq + (size_t)(s * KS) * HID_ + bn * 64, HID_,
                  qpart + (size_t)s * (N_AG * HID_) + bm * 128 * HID_ + bn * 64, HID_,
                  KS);
}

// qreduce: q[m,h] = bq[h] + sum_s qpart[s][m][h]   (f32 out for qkgemm staging)
__global__ __launch_bounds__(256) void qreduce(const _Float16* __restrict__ qpart,
                                               const float* __restrict__ bq,
                                               float* __restrict__ q)
{
    const int e = blockIdx.x * 512 + threadIdx.x * 2;   // grid 512
    float a0 = bq[e & (HID_ - 1)], a1 = bq[(e + 1) & (HID_ - 1)];
#pragma unroll
    for (int s = 0; s < SPLITQ; ++s) {
        f16x2 p = *(const f16x2*)(qpart + (size_t)s * (N_AG * HID_) + e);
        a0 += (float)p[0];
        a1 += (float)p[1];
    }
    q[e] = a0;
    q[e + 1] = a1;
}

// qkgemm: qk[n][c] = sum_h q[n,h] * Wk[c,h].  Both operands [row][k] f32.
// Tile 64x64, waves 2x2 (wave 32x32), K=512, grid 256 (1/CU even).
__global__ __launch_bounds__(256, 4) void qkgemm(const float* __restrict__ q,
                                                 const float* __restrict__ Wk,
                                                 _Float16* __restrict__ qk)
{
    __shared__ __align__(16) _Float16 smem[4 * 64 * LDS_K];   // As[2] | Bs[2]
    _Float16* As = smem;
    _Float16* Bs = smem + 2 * 64 * LDS_K;
    const int tid = threadIdx.x;
    const int lane = tid & 63;
    const int wid = tid >> 6;
    const int wr = wid >> 1;
    const int wc = wid & 1;
    const int r15 = lane & 15;
    const int kblk = (lane >> 4) << 3;

    const int b = blockIdx.x;
    const int w = (b & 7) * 32 + (b >> 3);    // 256 = 8 chunks of 32
    const int bm = w >> 5;                    // 0..7 agent-tile
    const int bn = w & 31;                    // 0..31 c-tile

    // staging: tid<128 -> A (q rows), tid>=128 -> B (Wk rows); 16 floats each
    const bool isB = tid >= 128;
    const int rt = tid & 127;
    const int srow = rt >> 1;
    const int skh = (rt & 1) << 4;
    const float* gp = (isB ? Wk + (size_t)(bn * 64) * HID_ : q + (size_t)(bm * 64) * HID_)
                      + (size_t)srow * HID_ + skh;
    _Float16* lbase = (isB ? Bs : As) + srow * LDS_K + skh;

    f32x4 acc[2][2];
#pragma unroll
    for (int mi = 0; mi < 2; ++mi)
#pragma unroll
        for (int ni = 0; ni < 2; ++ni)
            acc[mi][ni] = (f32x4){0.f, 0.f, 0.f, 0.f};

    float4 rA[4], rB[4];
    auto load_stage = [&](float4 (&r)[4], int ks) {
#pragma unroll
        for (int i = 0; i < 4; ++i) r[i] = *(const float4*)(gp + ks + 4 * i);
    };
    auto write_stage = [&](float4 (&r)[4], int buf) {
        const float* f = (const float*)&r[0];
        f16x8 h0, h1;
#pragma unroll
        for (int i = 0; i < 8; ++i) { h0[i] = (_Float16)f[i]; h1[i] = (_Float16)f[8 + i]; }
        *(f16x8*)(lbase + buf * 64 * LDS_K) = h0;
        *(f16x8*)(lbase + buf * 64 * LDS_K + 8) = h1;
    };
    auto compute = [&](int buf) {
        const _Float16* ab = As + buf * 64 * LDS_K;
        const _Float16* bbp = Bs + buf * 64 * LDS_K;
        f16x8 af[2], bf[2];
#pragma unroll
        for (int mi = 0; mi < 2; ++mi)
            af[mi] = *(const f16x8*)(ab + (wr * 32 + mi * 16 + r15) * LDS_K + kblk);
#pragma unroll
        for (int ni = 0; ni < 2; ++ni)
            bf[ni] = *(const f16x8*)(bbp + (wc * 32 + ni * 16 + r15) * LDS_K + kblk);
#pragma unroll
        for (int mi = 0; mi < 2; ++mi)
#pragma unroll
            for (int ni = 0; ni < 2; ++ni)
                acc[mi][ni] = __builtin_amdgcn_mfma_f32_16x16x32_f16(
                    af[mi], bf[ni], acc[mi][ni], 0, 0, 0);
    };

    load_stage(rA, 0);
    load_stage(rB, 32);
    write_stage(rA, 0);
    __syncthreads();
    for (int t = 0; t < 16; t += 2) {
        if (t + 2 < 16) load_stage(rA, (t + 2) << 5);
        compute(0);
        if (t + 1 < 16) write_stage(rB, 1);
        __syncthreads();
        if (t + 3 < 16) load_stage(rB, (t + 3) << 5);
        compute(1);
        if (t + 2 < 16) write_stage(rA, 0);
        __syncthreads();
    }
#pragma unroll
    for (int mi = 0; mi < 2; ++mi)
#pragma unroll
        for (int ni = 0; ni < 2; ++ni) {
            const int row = bm * 64 + wr * 32 + mi * 16 + ((lane >> 4) << 2);
            const int col = bn * 64 + wc * 32 + ni * 16 + r15;
#pragma unroll
            for (int r = 0; r < 4; ++r)
                qk[(size_t)(row + r) * TAU_ + col] = (_Float16)acc[mi][ni][r];
        }
}

// svmix: per-agent fused scores -> softmax -> trajectory mix -> out-projection.
// score[t] = dot(taus[t,n,:], qk[n,:]); wmix = sum_t alpha_t * taus[t,n,:];
// out[n,:] = wmix @ Wv + bv  (via Wvt rows).  bk dropped: softmax-invariant.
__global__ __launch_bounds__(256) void svmix(const float* __restrict__ traj,
                                             const _Float16* __restrict__ qkm,
                                             const _Float16* __restrict__ Wvt,
                                             const float* __restrict__ bv,
                                             float* __restrict__ out)
{
    const int n = blockIdx.x;
    const int tid = threadIdx.x;
    const int w = tid >> 6;
    const int lane = tid & 63;
    __shared__ _Float16 qs[TAU_];
    __shared__ float scr[TRAJ];
    __shared__ float wmix[TAU_];

    *(f16x8*)(qs + tid * 8) = *(const f16x8*)(qkm + (size_t)n * TAU_ + tid * 8);
    __syncthreads();

    // pass1: 4 dots per wave (wave w -> t = w*4+tt), 2048-long, shuffle-reduce
#pragma unroll
    for (int tt = 0; tt < 4; ++tt) {
        const int t = w * 4 + tt;
        const float* tr = traj + (size_t)(t * N_AG + n) * TAU_;
        float p = 0.f;
#pragma unroll
        for (int i = 0; i < 8; ++i) {
            const int off = (i * 64 + lane) * 4;
            float4 a = *(const float4*)(tr + off);
            f16x4 qv = *(const f16x4*)(qs + off);
            p += a.x * (float)qv[0] + a.y * (float)qv[1]
               + a.z * (float)qv[2] + a.w * (float)qv[3];
        }
#pragma unroll
        for (int off = 32; off > 0; off >>= 1) p += __shfl_xor(p, off);
        if (lane == 0) scr[t] = p;
    }
    __syncthreads();

    const float inv = 0.04419417382415922f;  // 1/sqrt(512)
    float sv[TRAJ];
    float mx = -1e30f;
#pragma unroll
    for (int t = 0; t < TRAJ; ++t) { sv[t] = scr[t] * inv; mx = fmaxf(mx, sv[t]); }
    float ssum = 0.f;
#pragma unroll
    for (int t = 0; t < TRAJ; ++t) { sv[t] = expf(sv[t] - mx); ssum += sv[t]; }
    const float rs = 1.f / ssum;
#pragma unroll
    for (int t = 0; t < TRAJ; ++t) sv[t] *= rs;

    // pass2: wmix[c] = sum_t sv[t] * taus[t,n,c]; thread owns 8 c's
    {
        const int c0 = tid * 8;
        float a[8] = {0.f, 0.f, 0.f, 0.f, 0.f, 0.f, 0.f, 0.f};
#pragma unroll
        for (int t = 0; t < TRAJ; ++t) {
            const float* tr = traj + (size_t)(t * N_AG + n) * TAU_ + c0;
            float4 x0 = *(const float4*)(tr);
            float4 x1 = *(const float4*)(tr + 4);
            a[0] += sv[t] * x0.x; a[1] += sv[t] * x0.y;
            a[2] += sv[t] * x0.z; a[3] += sv[t] * x0.w;
            a[4] += sv[t] * x1.x; a[5] += sv[t] * x1.y;
            a[6] += sv[t] * x1.z; a[7] += sv[t] * x1.w;
        }
#pragma unroll
        for (int i = 0; i < 8; ++i) wmix[c0 + i] = a[i];
    }
    __syncthreads();

    // pass3: out[n][j] = dot(wmix, Wvt[j,:]) + bv[j]; wave handles 16 j's
#pragma unroll
    for (int jj = 0; jj < 16; ++jj) {
        const int j = w * 16 + jj;
        const _Float16* wr_ = Wvt + (size_t)j * TAU_;
        float p = 0.f;
#pragma unroll
        for (int i = 0; i < 8; ++i) {
            const int off = (i * 64 + lane) * 4;
            f16x4 wv = *(const f16x4*)(wr_ + off);
            float4 wm = *(const float4*)(wmix + off);
            p += wm.x * (float)wv[0] + wm.y * (float)wv[1]
               + wm.z * (float)wv[2] + wm.w * (float)wv[3];
        }
#pragma unroll
        for (int off = 32; off > 0; off >>= 1) p += __shfl_xor(p, off);
        if (lane == 0) out[n * DV_ + j] = p + bv[j];
    }
}

extern "C" void kernel_launch(void* const* d_in, const int* in_sizes, int n_in,
                              void* d_out, int out_size, void* d_ws, size_t ws_size,
                              hipStream_t stream)
{
    const float* traj = (const float*)d_in[0];  // [16,512,2048]
    const float* msgs = (const float*)d_in[1];  // [512, 32768]
    const float* Wq   = (const float*)d_in[2];  // [32768, 512]
    const float* bq   = (const float*)d_in[3];  // [512]
    const float* Wk   = (const float*)d_in[4];  // [2048, 512]  (rows are [c][h] -> direct B operand)
    const float* bk   = (const float*)d_in[5];  // [512]  UNUSED: q.bk is constant over t -> softmax-invariant
    const float* Wv   = (const float*)d_in[6];  // [2048, 64]
    const float* bv   = (const float*)d_in[7];  // [64]
    float* out = (float*)d_out;                 // [512, 64]
    (void)bk;

    // ws: qpart f16 [32][512][512] 16MB | q f32 [512][512] 1MB |
    //     qk f16 [512][2048] 2MB | Wvt f16 [64][2048] 256KB
    _Float16* qpart = (_Float16*)d_ws;
    float*    q     = (float*)(qpart + (size_t)SPLITQ * N_AG * HID_);
    _Float16* qk    = (_Float16*)(q + (size_t)N_AG * HID_);
    _Float16* Wvt   = qk + (size_t)N_AG * TAU_;

    prep<<<32, 256, 0, stream>>>(Wv, Wvt);
    qgemm<<<1024, 256, 0, stream>>>(msgs, Wq, qpart);
    qreduce<<<512, 256, 0, stream>>>(qpart, bq, q);
    qkgemm<<<256, 256, 0, stream>>>(q, Wk, qk);
    svmix<<<512, 256, 0, stream>>>(traj, qk, Wvt, bv, out);
}